// Round 1
// baseline (190.225 us; speedup 1.0000x reference)
//
#include <hip/hip_runtime.h>

// out[n,k,y,x] = sum_c grid[n,k,c,y/16,x/16] * guidemap[n,c,y,x]
// N=2, K=C=32, H=W=1024, block grid 64x64, block size 16x16.

namespace {
constexpr int NIMG = 2;
constexpr int K = 32;
constexpr int C = 32;
constexpr int HB = 64, WB = 64;   // block grid
constexpr int F1 = 16, F2 = 16;   // block size
constexpr int H = 1024, W = 1024;
constexpr int HW = H * W;
}

__global__ __launch_bounds__(512, 4) void gridup_kernel(
    const float* __restrict__ grd,   // [N][K][C][HB][WB]
    const float* __restrict__ gm,    // [N][C][H][W]
    float* __restrict__ out)         // [N][K][H][W]
{
    // Guide tile: [c][64 chunks of 4 px] = 32 KB. Matrix transposed [c][k] = 4 KB.
    __shared__ float4 sG4[C][64];
    __shared__ float4 sM4[C][K / 4];

    const int b   = blockIdx.x;
    const int n   = b >> 12;        // 4096 blocks per image
    const int rem = b & 4095;
    const int by  = rem >> 6;
    const int bx  = rem & 63;
    const int t   = threadIdx.x;    // 0..511

    // ---- stage guide tile: 2048 float4 chunks, coalesced (64B row segments)
    {
        const float* gbase = gm + (size_t)n * C * HW + (by * F1) * W + bx * F2;
        #pragma unroll
        for (int i = 0; i < 4; ++i) {
            const int e   = t + 512 * i;     // 0..2047
            const int c   = e >> 6;
            const int l   = e & 63;          // chunk within tile
            const int r   = l >> 2;          // row 0..15
            const int col = (l & 3) << 2;    // col offset 0,4,8,12
            sG4[c][l] = *reinterpret_cast<const float4*>(
                gbase + (size_t)c * HW + r * W + col);
        }
    }
    // ---- stage matrix transposed into sM4: flat float index = c*32 + k
    {
        const float* mb = grd + (size_t)n * (K * C * HB * WB) + by * WB + bx;
        float* sMf = reinterpret_cast<float*>(&sM4[0][0]);
        #pragma unroll
        for (int i = 0; i < 2; ++i) {
            const int e = t + 512 * i;       // 0..1023 ; e = c*32 + k
            const int k = e & 31;
            const int c = e >> 5;
            sMf[e] = mb[(size_t)(k * C + c) * (HB * WB)];
        }
    }
    __syncthreads();

    const int kg = t >> 6;   // wave id: k-group (4 k's)
    const int l  = t & 63;   // pixel chunk (4 px)

    float acc[4][4] = {};
    #pragma unroll
    for (int c = 0; c < C; ++c) {
        const float4 g = sG4[c][l];    // conflict-free: lanes stride 16B
        const float4 m = sM4[c][kg];   // wave-uniform broadcast
        const float gv[4] = {g.x, g.y, g.z, g.w};
        const float mv[4] = {m.x, m.y, m.z, m.w};
        #pragma unroll
        for (int dk = 0; dk < 4; ++dk) {
            #pragma unroll
            for (int p = 0; p < 4; ++p) {
                acc[dk][p] += mv[dk] * gv[p];
            }
        }
    }

    // ---- write out: 4 float4 stores per thread (64B row segments)
    const int r   = l >> 2;
    const int col = (l & 3) << 2;
    float* ob = out + ((size_t)n * K + kg * 4) * HW + (by * F1 + r) * W + bx * F2 + col;
    #pragma unroll
    for (int dk = 0; dk < 4; ++dk) {
        const float4 v = {acc[dk][0], acc[dk][1], acc[dk][2], acc[dk][3]};
        *reinterpret_cast<float4*>(ob + (size_t)dk * HW) = v;
    }
}

extern "C" void kernel_launch(void* const* d_in, const int* in_sizes, int n_in,
                              void* d_out, int out_size, void* d_ws, size_t ws_size,
                              hipStream_t stream) {
    const float* grd = (const float*)d_in[0];   // grid:     2*32*32*64*64
    const float* gm  = (const float*)d_in[1];   // guidemap: 2*32*1024*1024
    float* out = (float*)d_out;                 // 2*32*1024*1024 fp32

    const int nblocks = NIMG * HB * WB;         // 8192
    gridup_kernel<<<nblocks, 512, 0, stream>>>(grd, gm, out);
}